// Round 7
// baseline (966.586 us; speedup 1.0000x reference)
//
#include <hip/hip_runtime.h>
#include <hip/hip_bf16.h>
#include <math.h>

namespace {

constexpr int C = 128;       // channels
constexpr int K = 32;        // max degree
constexpr int TILE_M = 128;  // GEMM row tile
constexpr int COLB = 64;     // GEMM col tile (half of C -> 2 col-blocks)
constexpr int LDSW = 132;    // LDS row stride in floats (128 + 4 pad)
constexpr int NSLICE = 8;    // channel slices == XCD count
constexpr int SLICE_C = 16;  // channels per slice (32 B bf16 rows)
constexpr int NT = 128;      // nodes per gather tile
constexpr int SW = 68;       // GEMM bf16 staging row stride (ushorts, 64+4)

typedef int int4v __attribute__((ext_vector_type(4)));
typedef float float4v __attribute__((ext_vector_type(4)));
typedef unsigned short ushort8v __attribute__((ext_vector_type(8)));

__device__ __forceinline__ float bf2f(unsigned short u) {
    return __uint_as_float(((unsigned int)u) << 16);
}

// ---------------------------------------------------------------------------
// Kernel 0: invs[n] = 1/sqrt(1 + #valid neighbors). Block 0 also zeroes the
// per-slice padding row h[s][N][*] (gather's clamped index target).
// ---------------------------------------------------------------------------
__global__ __launch_bounds__(256) void deg_kernel(const int* __restrict__ edge,
                                                  float* __restrict__ invs,
                                                  unsigned int* __restrict__ hzero,
                                                  int N) {
    if (blockIdx.x == 0 && threadIdx.x < 64) {
        int s = threadIdx.x >> 3;
        int i = threadIdx.x & 7;
        size_t sst_u32 = (size_t)(N + 1) * SLICE_C / 2;  // uints per slice
        hzero[(size_t)s * sst_u32 + (size_t)N * SLICE_C / 2 + i] = 0u;
    }
    int t = threadIdx.x;
    int node = blockIdx.x * 8 + (t >> 5);
    int k = t & 31;
    int e = (node < N) ? edge[(size_t)node * K + k] : -1;
    unsigned long long m = __ballot(e >= 0);
    int lane = t & 63;
    unsigned int half = (lane < 32) ? (unsigned int)(m & 0xffffffffULL)
                                    : (unsigned int)(m >> 32);
    int c = __popc(half);
    if (k == 0 && node < N) invs[node] = 1.0f / sqrtf((float)(c + 1));
}

// ---------------------------------------------------------------------------
// Kernel 1: H[slice][n][c'] = bf16( (X[n] . W[ch]) * invs[n] )
// fp32 vector-ALU GEMM, 128x64 tile: half of W in LDS (33.8 KB -> 4
// blocks/CU), X canonical from global (16-lane broadcast, L1/L2-hit; 4
// resident waves/SIMD hide the latency -- round 6's 2 waves didn't).
// Epilogue stages bf16 in the dead Ws LDS, then coalesced 16 B stores to the
// 4 slice regions this col-block owns.
// ---------------------------------------------------------------------------
__global__ __launch_bounds__(256, 4) void gemm_scale_kernel(
    const float* __restrict__ X, const float* __restrict__ W,
    const float* __restrict__ invs, unsigned short* __restrict__ H, int N) {
    __shared__ float Ws[COLB * LDSW];  // 33.8 KB

    const int t = threadIdx.x;
    const int cb = blockIdx.x & 1;   // col-block: cols cb*64 .. cb*64+63
    const int rb = blockIdx.x >> 1;  // row-block
    const int n0 = rb * TILE_M;
    const size_t out_sst = (size_t)(N + 1) * SLICE_C;  // bf16 slice stride

    // Stage W rows cb*64 .. cb*64+63 (64x128 floats = 2048 float4).
    for (int p = t; p < COLB * C / 4; p += 256) {
        int row = p >> 5;
        int c4 = p & 31;
        float4 v = ((const float4*)W)[(size_t)(cb * COLB + row) * (C / 4) + c4];
        *(float4*)&Ws[row * LDSW + c4 * 4] = v;
    }
    __syncthreads();

    const int tx = t & 15;  // local col base: cols tx + 16*c, c<4
    const int ty = t >> 4;  // row base: rows ty + 16*r, r<8

    const float* xrow[8];
#pragma unroll
    for (int r = 0; r < 8; ++r) {
        int n = n0 + ty + r * 16;
        if (n > N - 1) n = N - 1;  // clamp; writes are guarded
        xrow[r] = X + (size_t)n * C;
    }

    float acc[8][4];
#pragma unroll
    for (int r = 0; r < 8; ++r)
#pragma unroll
        for (int c = 0; c < 4; ++c) acc[r][c] = 0.f;

    for (int i = 0; i < C; i += 4) {
        float4 a[8], b[4];
#pragma unroll
        for (int r = 0; r < 8; ++r) a[r] = *(const float4*)(xrow[r] + i);
#pragma unroll
        for (int c = 0; c < 4; ++c)
            b[c] = *(const float4*)&Ws[(tx + c * 16) * LDSW + i];
#pragma unroll
        for (int r = 0; r < 8; ++r)
#pragma unroll
            for (int c = 0; c < 4; ++c) {
                acc[r][c] += a[r].x * b[c].x;
                acc[r][c] += a[r].y * b[c].y;
                acc[r][c] += a[r].z * b[c].z;
                acc[r][c] += a[r].w * b[c].w;
            }
    }

    // ---- Epilogue: stage bf16 in dead Ws LDS, then coalesced slice stores.
    __syncthreads();
    unsigned short* st = (unsigned short*)Ws;  // [128][SW]
#pragma unroll
    for (int r = 0; r < 8; ++r) {
        int n = n0 + ty + r * 16;
        float s = invs[n < N ? n : N - 1];
#pragma unroll
        for (int c = 0; c < 4; ++c) {
            __hip_bfloat16 hv = __float2bfloat16(acc[r][c] * s);
            st[(ty + r * 16) * SW + tx + 16 * c] = *(unsigned short*)&hv;
        }
    }
    __syncthreads();
    {
        const int row = t >> 1;
        const int hf = t & 1;
        const int n = n0 + row;
        if (n < N) {
#pragma unroll
            for (int s2 = 0; s2 < 4; ++s2) {
                ushort8v vv = *(const ushort8v*)&st[row * SW + s2 * 16 + hf * 8];
                *(ushort8v*)(H + (size_t)(cb * 4 + s2) * out_sst +
                             (size_t)n * SLICE_C + hf * 8) = vv;
            }
        }
    }
}

// ---------------------------------------------------------------------------
// Kernel 2: channel-sliced gather + ELU, static split, batch-16 unconditional
// loads. slice = blockIdx & 7 pins each slice's blocks to one XCD (3.2 MB
// bf16 slice L2-resident; round-5/6 FETCH confirmed). Round 6 was Little's-
// law-bound (32 outstanding 32 B loads/SIMD x ~300cyc = 5.8 TB/s); batch 16
// at <=128 VGPR doubles in-flight bytes at the same 4-waves/SIMD tier.
// Output always canonical [N][C] fp32.
// ---------------------------------------------------------------------------
__global__ __launch_bounds__(256, 4) void gather_elu_kernel(
    const unsigned short* __restrict__ H, const int* __restrict__ edge,
    const float* __restrict__ invs, float* __restrict__ out, int N) {
    __shared__ int idx_s[NT][33];

    const int t = threadIdx.x;
    const int s = blockIdx.x & (NSLICE - 1);
    const int grp = blockIdx.x >> 3;
    const int ngrp = 256;
    const int ntiles = (N + NT - 1) / NT;
    const size_t h_sst = (size_t)(N + 1) * SLICE_C;  // bf16 slice stride
    const unsigned short* hs = H + (size_t)s * h_sst;
    const int nl = t >> 1;
    const int half = t & 1;

    for (int tt = grp; tt < ntiles; tt += ngrp) {
        const int base = tt * NT;

        // Stage 128 nodes' edge lists (16 KB), nontemporal coalesced loads.
#pragma unroll
        for (int ii = 0; ii < 4; ++ii) {
            int p = (ii * 256 + t) * 4;  // flat int index into NT*K
            int r = p >> 5;              // K == 32
            int c0 = p & 31;
            int node = base + r;
            int4v e = {-1, -1, -1, -1};
            if (node < N)
                e = __builtin_nontemporal_load(
                    (const int4v*)(edge + (size_t)node * K + c0));
            idx_s[r][c0 + 0] = e.x;
            idx_s[r][c0 + 1] = e.y;
            idx_s[r][c0 + 2] = e.z;
            idx_s[r][c0 + 3] = e.w;
        }
        __syncthreads();

        const int node = base + nl;
        {
            const unsigned short* hh = hs + half * 8;
            float acc[8];
#pragma unroll
            for (int i = 0; i < 8; ++i) acc[i] = 0.f;
#pragma unroll
            for (int k0 = 0; k0 < K; k0 += 16) {
                ushort8v v[16];
#pragma unroll
                for (int u = 0; u < 16; ++u) {
                    int j = idx_s[nl][k0 + u];
                    j = (j < 0) ? N : j;  // row N is all zeros
                    v[u] = *(const ushort8v*)(hh + (size_t)j * SLICE_C);
                }
#pragma unroll
                for (int u = 0; u < 16; ++u)
#pragma unroll
                    for (int i = 0; i < 8; ++i) acc[i] += bf2f(v[u][i]);
            }
            if (node < N) {
                ushort8v sv = *(const ushort8v*)(hh + (size_t)node * SLICE_C);
                float sc = invs[node];
                float r[8];
#pragma unroll
                for (int i = 0; i < 8; ++i) {
                    float x = (acc[i] + bf2f(sv[i])) * sc;
                    r[i] = x > 0.f ? x : expm1f(x);
                }
                float* dst = out + (size_t)node * C + s * SLICE_C + half * 8;
                float4v lo = {r[0], r[1], r[2], r[3]};
                float4v hi = {r[4], r[5], r[6], r[7]};
                __builtin_nontemporal_store(lo, (float4v*)dst);
                __builtin_nontemporal_store(hi, (float4v*)(dst + 4));
            }
        }
        __syncthreads();  // idx_s reads done before next tile's staging
    }
}

}  // namespace

extern "C" void kernel_launch(void* const* d_in, const int* in_sizes, int n_in,
                              void* d_out, int out_size, void* d_ws, size_t ws_size,
                              hipStream_t stream) {
    const float* x = (const float*)d_in[0];
    const int* edge = (const int*)d_in[1];
    const float* W1 = (const float*)d_in[2];
    const float* W2 = (const float*)d_in[3];
    float* out = (float*)d_out;
    const int N = in_sizes[0] / C;  // 100000

    // Workspace: invs [N floats] | h [8 x (N+1) x 16 bf16, slice-major]
    char* ws = (char*)d_ws;
    float* invs = (float*)ws;
    size_t invs_bytes = ((size_t)N * sizeof(float) + 255) & ~(size_t)255;
    unsigned short* h = (unsigned short*)(ws + invs_bytes);

    const int nodeBlocks = (N + 7) / 8;
    const int gemmBlocks = ((N + TILE_M - 1) / TILE_M) * 2;  // x2 col-blocks
    const int gatherBlocks = 2048;  // 256 groups x 8 slices

    deg_kernel<<<nodeBlocks, 256, 0, stream>>>(edge, invs, (unsigned int*)h, N);
    // Layer 1: x -> h (sliced bf16) -> act (canonical fp32, in d_out)
    gemm_scale_kernel<<<gemmBlocks, 256, 0, stream>>>(x, W1, invs, h, N);
    gather_elu_kernel<<<gatherBlocks, 256, 0, stream>>>(h, edge, invs, out, N);
    // Layer 2: act (canonical, d_out) -> h (sliced bf16) -> out (canonical)
    gemm_scale_kernel<<<gemmBlocks, 256, 0, stream>>>(out, W2, invs, h, N);
    gather_elu_kernel<<<gatherBlocks, 256, 0, stream>>>(h, edge, invs, out, N);
}

// Round 8
// 440.899 us; speedup vs baseline: 2.1923x; 2.1923x over previous
//
#include <hip/hip_runtime.h>
#include <hip/hip_bf16.h>
#include <math.h>

namespace {

constexpr int C = 128;       // channels
constexpr int K = 32;        // max degree
constexpr int TILE_M = 128;  // GEMM row tile
constexpr int COLB = 64;     // GEMM col tile (2 col-blocks)
constexpr int LDSW = 132;    // LDS W row stride in floats (128 + 4 pad)
constexpr int SW = 68;       // GEMM bf16 staging row stride (ushorts, 64+4)

typedef float float4v __attribute__((ext_vector_type(4)));
typedef unsigned short ushort8v __attribute__((ext_vector_type(8)));

__device__ __forceinline__ float bf2f(unsigned short u) {
    return __uint_as_float(((unsigned int)u) << 16);
}

// ---------------------------------------------------------------------------
// Kernel 0: invs[n] = 1/sqrt(1 + #valid neighbors). Block 0 also zeroes the
// padding row h[N][*] (the gather's clamped-index target).
// ---------------------------------------------------------------------------
__global__ __launch_bounds__(256) void deg_kernel(const int* __restrict__ edge,
                                                  float* __restrict__ invs,
                                                  unsigned int* __restrict__ hzero,
                                                  int N) {
    if (blockIdx.x == 0 && threadIdx.x < 64) {
        // row N of h: 128 bf16 = 64 uints of zeros
        hzero[(size_t)N * (C / 2) + threadIdx.x] = 0u;
    }
    int t = threadIdx.x;
    int node = blockIdx.x * 8 + (t >> 5);
    int k = t & 31;
    int e = (node < N) ? edge[(size_t)node * K + k] : -1;
    unsigned long long m = __ballot(e >= 0);
    int lane = t & 63;
    unsigned int half = (lane < 32) ? (unsigned int)(m & 0xffffffffULL)
                                    : (unsigned int)(m >> 32);
    int c = __popc(half);
    if (k == 0 && node < N) invs[node] = 1.0f / sqrtf((float)(c + 1));
}

// ---------------------------------------------------------------------------
// Kernel 1: H[n][ch] = bf16( (X[n] . W[ch]) * invs[n] ),  canonical [N+1][128]
// fp32 vector-ALU GEMM, 128x64 tile: half of W in LDS (33.8 KB), X canonical
// from global (16-lane broadcast, L1-hit) with a 1-deep register prefetch
// (round-5-proven) to hide load latency. Epilogue stages bf16 in the dead Ws
// LDS then writes coalesced 16 B stores.
// ---------------------------------------------------------------------------
__global__ __launch_bounds__(256) void gemm_scale_kernel(
    const float* __restrict__ X, const float* __restrict__ W,
    const float* __restrict__ invs, unsigned short* __restrict__ H, int N) {
    __shared__ float Ws[COLB * LDSW];  // 33.8 KB

    const int t = threadIdx.x;
    const int cb = blockIdx.x & 1;   // col-block: cols cb*64 .. cb*64+63
    const int rb = blockIdx.x >> 1;  // row-block
    const int n0 = rb * TILE_M;

    // Stage W rows cb*64 .. cb*64+63 (64x128 floats = 2048 float4).
    for (int p = t; p < COLB * C / 4; p += 256) {
        int row = p >> 5;
        int c4 = p & 31;
        float4 v = ((const float4*)W)[(size_t)(cb * COLB + row) * (C / 4) + c4];
        *(float4*)&Ws[row * LDSW + c4 * 4] = v;
    }
    __syncthreads();

    const int tx = t & 15;  // local col base: cols tx + 16*c, c<4
    const int ty = t >> 4;  // row base: rows ty + 16*r, r<8

    const float* xrow[8];
#pragma unroll
    for (int r = 0; r < 8; ++r) {
        int n = n0 + ty + r * 16;
        if (n > N - 1) n = N - 1;  // clamp; writes are guarded
        xrow[r] = X + (size_t)n * C;
    }

    float acc[8][4];
#pragma unroll
    for (int r = 0; r < 8; ++r)
#pragma unroll
        for (int c = 0; c < 4; ++c) acc[r][c] = 0.f;

    float4 a[8], an[8];
#pragma unroll
    for (int r = 0; r < 8; ++r) an[r] = *(const float4*)(xrow[r]);

#pragma unroll 4
    for (int i = 0; i < C; i += 4) {
#pragma unroll
        for (int r = 0; r < 8; ++r) a[r] = an[r];
        if (i + 4 < C) {
#pragma unroll
            for (int r = 0; r < 8; ++r)
                an[r] = *(const float4*)(xrow[r] + i + 4);
        }
        float4 b[4];
#pragma unroll
        for (int c = 0; c < 4; ++c)
            b[c] = *(const float4*)&Ws[(tx + c * 16) * LDSW + i];
#pragma unroll
        for (int r = 0; r < 8; ++r)
#pragma unroll
            for (int c = 0; c < 4; ++c) {
                acc[r][c] += a[r].x * b[c].x;
                acc[r][c] += a[r].y * b[c].y;
                acc[r][c] += a[r].z * b[c].z;
                acc[r][c] += a[r].w * b[c].w;
            }
    }

    // ---- Epilogue: stage bf16 in dead Ws LDS, then coalesced stores.
    __syncthreads();
    unsigned short* st = (unsigned short*)Ws;  // [128][SW]
#pragma unroll
    for (int r = 0; r < 8; ++r) {
        int n = n0 + ty + r * 16;
        float s = invs[n < N ? n : N - 1];
#pragma unroll
        for (int c = 0; c < 4; ++c) {
            __hip_bfloat16 hv = __float2bfloat16(acc[r][c] * s);
            st[(ty + r * 16) * SW + tx + 16 * c] = *(unsigned short*)&hv;
        }
    }
    __syncthreads();
    {
        const int row = t >> 1;  // 0..127
        const int hf = t & 1;    // half of the 64-col span
        const int n = n0 + row;
        if (n < N) {
#pragma unroll
            for (int q = 0; q < 2; ++q) {
                ushort8v vv =
                    *(const ushort8v*)&st[row * SW + hf * 32 + q * 8 + (hf ^ q) * 16];
                *(ushort8v*)(H + (size_t)n * C + cb * COLB + hf * 32 + q * 8 +
                             (hf ^ q) * 16) = vv;
            }
#pragma unroll
            for (int q = 0; q < 2; ++q) {
                ushort8v vv =
                    *(const ushort8v*)&st[row * SW + hf * 32 + q * 8 + ((hf ^ q) ^ 1) * 16];
                *(ushort8v*)(H + (size_t)n * C + cb * COLB + hf * 32 + q * 8 +
                             ((hf ^ q) ^ 1) * 16) = vv;
            }
        }
    }
}

// ---------------------------------------------------------------------------
// Kernel 2: canonical gather + ELU. h rows are 256 B bf16 (4 full 64 B lines,
// 100% line utilization — round 6's 32 B sliced rows doubled the L2 request
// count; canonical was faster). 25.6 MB h is L3-resident. MLP: padding index
// -1 clamps to zero-row N, so all K loads issue unconditionally in batches of
// 16 (8 B/lane => only 32 VGPRs in flight; round 7's 16x16B spilled).
// 8 nodes per 256-thread block, 32 lanes/node x ushort4.
// ---------------------------------------------------------------------------
__global__ __launch_bounds__(256) void gather_elu_kernel(
    const unsigned short* __restrict__ H, const int* __restrict__ edge,
    const float* __restrict__ invs, float* __restrict__ out, int N) {
    __shared__ int idx_s[8][K];

    const int t = threadIdx.x;
    const int g = t >> 5;
    const int lane32 = t & 31;
    const int node = blockIdx.x * 8 + g;

    idx_s[g][lane32] = (node < N) ? edge[(size_t)node * K + lane32] : -1;
    __syncthreads();
    if (node >= N) return;

    const unsigned short* hp = H + lane32 * 4;  // this lane's 4 channels
    float a0 = 0.f, a1 = 0.f, a2 = 0.f, a3 = 0.f;

#pragma unroll
    for (int k0 = 0; k0 < K; k0 += 16) {
        ushort4 v[16];
#pragma unroll
        for (int u = 0; u < 16; ++u) {
            int j = idx_s[g][k0 + u];
            j = (j < 0) ? N : j;  // row N is all zeros
            v[u] = *(const ushort4*)(hp + (size_t)j * C);
        }
#pragma unroll
        for (int u = 0; u < 16; ++u) {
            a0 += bf2f(v[u].x);
            a1 += bf2f(v[u].y);
            a2 += bf2f(v[u].z);
            a3 += bf2f(v[u].w);
        }
    }

    ushort4 sv = *(const ushort4*)(hp + (size_t)node * C);
    float s = invs[node];
    float r0 = (a0 + bf2f(sv.x)) * s;
    float r1 = (a1 + bf2f(sv.y)) * s;
    float r2 = (a2 + bf2f(sv.z)) * s;
    float r3 = (a3 + bf2f(sv.w)) * s;
    r0 = r0 > 0.f ? r0 : expm1f(r0);
    r1 = r1 > 0.f ? r1 : expm1f(r1);
    r2 = r2 > 0.f ? r2 : expm1f(r2);
    r3 = r3 > 0.f ? r3 : expm1f(r3);
    float4v rv = {r0, r1, r2, r3};
    *(float4v*)(out + (size_t)node * C + lane32 * 4) = rv;
}

}  // namespace

extern "C" void kernel_launch(void* const* d_in, const int* in_sizes, int n_in,
                              void* d_out, int out_size, void* d_ws, size_t ws_size,
                              hipStream_t stream) {
    const float* x = (const float*)d_in[0];
    const int* edge = (const int*)d_in[1];
    const float* W1 = (const float*)d_in[2];
    const float* W2 = (const float*)d_in[3];
    float* out = (float*)d_out;
    const int N = in_sizes[0] / C;  // 100000

    // Workspace: invs [N floats] | h [(N+1) x 128 bf16, canonical]
    char* ws = (char*)d_ws;
    float* invs = (float*)ws;
    size_t invs_bytes = ((size_t)N * sizeof(float) + 255) & ~(size_t)255;
    unsigned short* h = (unsigned short*)(ws + invs_bytes);

    const int nodeBlocks = (N + 7) / 8;
    const int gemmBlocks = ((N + TILE_M - 1) / TILE_M) * 2;  // x2 col-blocks

    deg_kernel<<<nodeBlocks, 256, 0, stream>>>(edge, invs, (unsigned int*)h, N);
    // Layer 1: x -> h (bf16) -> act (fp32, in d_out)
    gemm_scale_kernel<<<gemmBlocks, 256, 0, stream>>>(x, W1, invs, h, N);
    gather_elu_kernel<<<nodeBlocks, 256, 0, stream>>>(h, edge, invs, out, N);
    // Layer 2: act (d_out) -> h (bf16) -> out
    gemm_scale_kernel<<<gemmBlocks, 256, 0, stream>>>(out, W2, invs, h, N);
    gather_elu_kernel<<<nodeBlocks, 256, 0, stream>>>(h, edge, invs, out, N);
}

// Round 9
// 357.351 us; speedup vs baseline: 2.7049x; 1.2338x over previous
//
#include <hip/hip_runtime.h>
#include <hip/hip_bf16.h>
#include <math.h>

namespace {

constexpr int C = 128;       // channels
constexpr int K = 32;        // max degree
constexpr int TILE_M = 128;  // GEMM row tile
constexpr int COLB = 64;     // GEMM col tile (2 col-blocks)
constexpr int LDSW = 132;    // LDS W row stride in floats (128 + 4 pad)
constexpr int SW = 68;       // GEMM bf16 staging row stride (ushorts, 64+4)

typedef float float4v __attribute__((ext_vector_type(4)));
typedef unsigned short ushort8v __attribute__((ext_vector_type(8)));

__device__ __forceinline__ float bf2f(unsigned short u) {
    return __uint_as_float(((unsigned int)u) << 16);
}

// ---------------------------------------------------------------------------
// Kernel 0: invs[n] = 1/sqrt(1 + #valid neighbors). Block 0 also zeroes the
// padding row h[N][*] (the gather's clamped-index target).
// ---------------------------------------------------------------------------
__global__ __launch_bounds__(256) void deg_kernel(const int* __restrict__ edge,
                                                  float* __restrict__ invs,
                                                  unsigned int* __restrict__ hzero,
                                                  int N) {
    if (blockIdx.x == 0 && threadIdx.x < 64) {
        // row N of h: 128 bf16 = 64 uints of zeros
        hzero[(size_t)N * (C / 2) + threadIdx.x] = 0u;
    }
    int t = threadIdx.x;
    int node = blockIdx.x * 8 + (t >> 5);
    int k = t & 31;
    int e = (node < N) ? edge[(size_t)node * K + k] : -1;
    unsigned long long m = __ballot(e >= 0);
    int lane = t & 63;
    unsigned int half = (lane < 32) ? (unsigned int)(m & 0xffffffffULL)
                                    : (unsigned int)(m >> 32);
    int c = __popc(half);
    if (k == 0 && node < N) invs[node] = 1.0f / sqrtf((float)(c + 1));
}

// ---------------------------------------------------------------------------
// Kernel 1: H[n][ch] = bf16( (X[n] . W[ch]) * invs[n] ),  canonical [N+1][128]
// fp32 vector-ALU GEMM, 128x64 tile: half of W in LDS (33.8 KB -> 4
// blocks/CU), X read from global (16-lane broadcast, L1-resident working
// set of 128 lines). NO register prefetch and __launch_bounds__(256,4):
// round 8's an[8] prefetch pushed VGPR to 144, crossing the 128-VGPR tier
// (waves/SIMD halve at 64/128/256) -> 2 waves/SIMD -> latency-bound 120 us.
// Round-7 config measured ~58 us.
// Epilogue stages bf16 in the dead Ws LDS, then 16 B coalesced stores.
// ---------------------------------------------------------------------------
__global__ __launch_bounds__(256, 4) void gemm_scale_kernel(
    const float* __restrict__ X, const float* __restrict__ W,
    const float* __restrict__ invs, unsigned short* __restrict__ H, int N) {
    __shared__ float Ws[COLB * LDSW];  // 33.8 KB

    const int t = threadIdx.x;
    const int cb = blockIdx.x & 1;   // col-block: cols cb*64 .. cb*64+63
    const int rb = blockIdx.x >> 1;  // row-block
    const int n0 = rb * TILE_M;

    // Stage W rows cb*64 .. cb*64+63 (64x128 floats = 2048 float4).
    for (int p = t; p < COLB * C / 4; p += 256) {
        int row = p >> 5;
        int c4 = p & 31;
        float4 v = ((const float4*)W)[(size_t)(cb * COLB + row) * (C / 4) + c4];
        *(float4*)&Ws[row * LDSW + c4 * 4] = v;
    }
    __syncthreads();

    const int tx = t & 15;  // local col base: cols tx + 16*c, c<4
    const int ty = t >> 4;  // row base: rows ty + 16*r, r<8

    const float* xrow[8];
#pragma unroll
    for (int r = 0; r < 8; ++r) {
        int n = n0 + ty + r * 16;
        if (n > N - 1) n = N - 1;  // clamp; writes are guarded
        xrow[r] = X + (size_t)n * C;
    }

    float acc[8][4];
#pragma unroll
    for (int r = 0; r < 8; ++r)
#pragma unroll
        for (int c = 0; c < 4; ++c) acc[r][c] = 0.f;

    for (int i = 0; i < C; i += 4) {
        float4 a[8], b[4];
#pragma unroll
        for (int r = 0; r < 8; ++r) a[r] = *(const float4*)(xrow[r] + i);
#pragma unroll
        for (int c = 0; c < 4; ++c)
            b[c] = *(const float4*)&Ws[(tx + c * 16) * LDSW + i];
#pragma unroll
        for (int r = 0; r < 8; ++r)
#pragma unroll
            for (int c = 0; c < 4; ++c) {
                acc[r][c] += a[r].x * b[c].x;
                acc[r][c] += a[r].y * b[c].y;
                acc[r][c] += a[r].z * b[c].z;
                acc[r][c] += a[r].w * b[c].w;
            }
    }

    // ---- Epilogue: stage bf16 in dead Ws LDS, then coalesced stores.
    __syncthreads();
    unsigned short* st = (unsigned short*)Ws;  // [128][SW]
#pragma unroll
    for (int r = 0; r < 8; ++r) {
        int n = n0 + ty + r * 16;
        float s = invs[n < N ? n : N - 1];
#pragma unroll
        for (int c = 0; c < 4; ++c) {
            __hip_bfloat16 hv = __float2bfloat16(acc[r][c] * s);
            st[(ty + r * 16) * SW + tx + 16 * c] = *(unsigned short*)&hv;
        }
    }
    __syncthreads();
    {
        const int row = t >> 1;  // 0..127
        const int hf = t & 1;    // which 32-ushort half of the 64-col span
        const int n = n0 + row;
        if (n < N) {
#pragma unroll
            for (int q = 0; q < 4; ++q) {
                ushort8v vv = *(const ushort8v*)&st[row * SW + hf * 32 + q * 8];
                *(ushort8v*)(H + (size_t)n * C + cb * COLB + hf * 32 + q * 8) =
                    vv;
            }
        }
    }
}

// ---------------------------------------------------------------------------
// Kernel 2: canonical gather + ELU (UNCHANGED from round 8, ~95 us).
// h rows are 256 B bf16 (full 64 B lines). 25.6 MB h is L3-resident.
// Padding index -1 clamps to zero-row N -> all K loads unconditional in
// batches of 16 x 8 B (32 VGPRs in flight, no spill).
// ---------------------------------------------------------------------------
__global__ __launch_bounds__(256) void gather_elu_kernel(
    const unsigned short* __restrict__ H, const int* __restrict__ edge,
    const float* __restrict__ invs, float* __restrict__ out, int N) {
    __shared__ int idx_s[8][K];

    const int t = threadIdx.x;
    const int g = t >> 5;
    const int lane32 = t & 31;
    const int node = blockIdx.x * 8 + g;

    idx_s[g][lane32] = (node < N) ? edge[(size_t)node * K + lane32] : -1;
    __syncthreads();
    if (node >= N) return;

    const unsigned short* hp = H + lane32 * 4;  // this lane's 4 channels
    float a0 = 0.f, a1 = 0.f, a2 = 0.f, a3 = 0.f;

#pragma unroll
    for (int k0 = 0; k0 < K; k0 += 16) {
        ushort4 v[16];
#pragma unroll
        for (int u = 0; u < 16; ++u) {
            int j = idx_s[g][k0 + u];
            j = (j < 0) ? N : j;  // row N is all zeros
            v[u] = *(const ushort4*)(hp + (size_t)j * C);
        }
#pragma unroll
        for (int u = 0; u < 16; ++u) {
            a0 += bf2f(v[u].x);
            a1 += bf2f(v[u].y);
            a2 += bf2f(v[u].z);
            a3 += bf2f(v[u].w);
        }
    }

    ushort4 sv = *(const ushort4*)(hp + (size_t)node * C);
    float s = invs[node];
    float r0 = (a0 + bf2f(sv.x)) * s;
    float r1 = (a1 + bf2f(sv.y)) * s;
    float r2 = (a2 + bf2f(sv.z)) * s;
    float r3 = (a3 + bf2f(sv.w)) * s;
    r0 = r0 > 0.f ? r0 : expm1f(r0);
    r1 = r1 > 0.f ? r1 : expm1f(r1);
    r2 = r2 > 0.f ? r2 : expm1f(r2);
    r3 = r3 > 0.f ? r3 : expm1f(r3);
    float4v rv = {r0, r1, r2, r3};
    *(float4v*)(out + (size_t)node * C + lane32 * 4) = rv;
}

}  // namespace

extern "C" void kernel_launch(void* const* d_in, const int* in_sizes, int n_in,
                              void* d_out, int out_size, void* d_ws, size_t ws_size,
                              hipStream_t stream) {
    const float* x = (const float*)d_in[0];
    const int* edge = (const int*)d_in[1];
    const float* W1 = (const float*)d_in[2];
    const float* W2 = (const float*)d_in[3];
    float* out = (float*)d_out;
    const int N = in_sizes[0] / C;  // 100000

    // Workspace: invs [N floats] | h [(N+1) x 128 bf16, canonical]
    char* ws = (char*)d_ws;
    float* invs = (float*)ws;
    size_t invs_bytes = ((size_t)N * sizeof(float) + 255) & ~(size_t)255;
    unsigned short* h = (unsigned short*)(ws + invs_bytes);

    const int nodeBlocks = (N + 7) / 8;
    const int gemmBlocks = ((N + TILE_M - 1) / TILE_M) * 2;  // x2 col-blocks

    deg_kernel<<<nodeBlocks, 256, 0, stream>>>(edge, invs, (unsigned int*)h, N);
    // Layer 1: x -> h (bf16) -> act (fp32, in d_out)
    gemm_scale_kernel<<<gemmBlocks, 256, 0, stream>>>(x, W1, invs, h, N);
    gather_elu_kernel<<<nodeBlocks, 256, 0, stream>>>(h, edge, invs, out, N);
    // Layer 2: act (d_out) -> h (bf16) -> out
    gemm_scale_kernel<<<gemmBlocks, 256, 0, stream>>>(out, W2, invs, h, N);
    gather_elu_kernel<<<nodeBlocks, 256, 0, stream>>>(h, edge, invs, out, N);
}

// Round 10
// 279.318 us; speedup vs baseline: 3.4605x; 1.2794x over previous
//
#include <hip/hip_runtime.h>
#include <hip/hip_bf16.h>
#include <math.h>

namespace {

constexpr int C = 128;  // channels
constexpr int K = 32;   // max degree

typedef float float4v __attribute__((ext_vector_type(4)));
typedef short short8v __attribute__((ext_vector_type(8)));  // 8 bf16 (4 VGPR)

__device__ __forceinline__ float bf2f(unsigned short u) {
    return __uint_as_float(((unsigned int)u) << 16);
}
__device__ __forceinline__ unsigned short f2bf(float x) {
    __hip_bfloat16 h = __float2bfloat16(x);
    return *(unsigned short*)&h;
}

// ---------------------------------------------------------------------------
// Kernel 0: invs[n] = 1/sqrt(1 + #valid neighbors). Block 0 also zeroes the
// padding row h[N][*] (the gather's clamped-index target).
// ---------------------------------------------------------------------------
__global__ __launch_bounds__(256) void deg_kernel(const int* __restrict__ edge,
                                                  float* __restrict__ invs,
                                                  unsigned int* __restrict__ hzero,
                                                  int N) {
    if (blockIdx.x == 0 && threadIdx.x < 64) {
        hzero[(size_t)N * (C / 2) + threadIdx.x] = 0u;  // row N: 128 bf16 zeros
    }
    int t = threadIdx.x;
    int node = blockIdx.x * 8 + (t >> 5);
    int k = t & 31;
    int e = (node < N) ? edge[(size_t)node * K + k] : -1;
    unsigned long long m = __ballot(e >= 0);
    int lane = t & 63;
    unsigned int half = (lane < 32) ? (unsigned int)(m & 0xffffffffULL)
                                    : (unsigned int)(m >> 32);
    int c = __popc(half);
    if (k == 0 && node < N) invs[node] = 1.0f / sqrtf((float)(c + 1));
}

// ---------------------------------------------------------------------------
// Kernel 1: H[n][ch] = bf16( (X[n] . W[ch]) * invs[n] ),  H canonical [N+1][128]
// Split-bf16 MFMA GEMM (~fp32 accuracy): x@W ~= xh@Wh + xl@Wh + xh@Wl with
// xh=bf16(x), xl=bf16(x-xh). 3x MFMA work but matrix pipe is ~100x the fp32
// VALU. Block: 4 waves x 32 rows = 128 rows, all 128 cols. W staged once as
// Wh/Wl bf16 [128][136] in LDS (69.6 KB -> 2 blocks/CU); A-fragments loaded
// direct from global with in-register split (quarter-waves cover both halves
// of each 64 B line -> full line utilization).
// mfma_f32_16x16x32_bf16 layouts (learn_hip-verified): A/B lane l: row/col =
// l&15, k = (l>>4)*8 + j. C/D: col = l&15, row = (l>>4)*4 + reg.
// ---------------------------------------------------------------------------
__global__ __launch_bounds__(256, 2) void gemm_mfma_kernel(
    const float* __restrict__ X, const float* __restrict__ W,
    const float* __restrict__ invs, unsigned short* __restrict__ H, int N) {
    __shared__ unsigned short Whl[2][C][136];  // [hi/lo][out_ch][in_ch], padded

    const int t = threadIdx.x;
    const int n0 = blockIdx.x * 128;

    // Stage W (128x128 fp32) as hi/lo bf16. 4096 float4 / 256 threads.
    for (int p = t; p < C * C / 4; p += 256) {
        int row = p >> 5;
        int c4 = (p & 31) * 4;
        float4 w = ((const float4*)W)[p];
        float wv[4] = {w.x, w.y, w.z, w.w};
#pragma unroll
        for (int j = 0; j < 4; ++j) {
            unsigned short hb = f2bf(wv[j]);
            Whl[0][row][c4 + j] = hb;
            Whl[1][row][c4 + j] = f2bf(wv[j] - bf2f(hb));
        }
    }
    __syncthreads();

    const int wv = t >> 6;        // wave 0..3
    const int l = t & 63;
    const int lm = l & 15;        // row (A) / col (B) within 16-tile
    const int lk = l >> 4;        // k-group (x8)
    const int rbase = n0 + wv * 32;

    int rowA0 = rbase + lm;
    int rowA1 = rbase + 16 + lm;
    rowA0 = rowA0 < N ? rowA0 : N - 1;
    rowA1 = rowA1 < N ? rowA1 : N - 1;
    const float* xp0 = X + (size_t)rowA0 * C;
    const float* xp1 = X + (size_t)rowA1 * C;

    float4v acc[2][8];
#pragma unroll
    for (int rt = 0; rt < 2; ++rt)
#pragma unroll
        for (int ct = 0; ct < 8; ++ct) acc[rt][ct] = {0.f, 0.f, 0.f, 0.f};

#pragma unroll
    for (int ks = 0; ks < 4; ++ks) {
        const int kb = ks * 32 + lk * 8;
        // Load 8 fp32 per row-tile, split into bf16 hi + lo fragments.
        float xr0[8], xr1[8];
        *(float4v*)&xr0[0] = *(const float4v*)(xp0 + kb);
        *(float4v*)&xr0[4] = *(const float4v*)(xp0 + kb + 4);
        *(float4v*)&xr1[0] = *(const float4v*)(xp1 + kb);
        *(float4v*)&xr1[4] = *(const float4v*)(xp1 + kb + 4);
        short8v ah0, al0, ah1, al1;
#pragma unroll
        for (int j = 0; j < 8; ++j) {
            unsigned short h0 = f2bf(xr0[j]);
            unsigned short h1 = f2bf(xr1[j]);
            ah0[j] = (short)h0;
            ah1[j] = (short)h1;
            al0[j] = (short)f2bf(xr0[j] - bf2f(h0));
            al1[j] = (short)f2bf(xr1[j] - bf2f(h1));
        }
#pragma unroll
        for (int ct = 0; ct < 8; ++ct) {
            short8v bh = *(const short8v*)&Whl[0][ct * 16 + lm][kb];
            short8v bl = *(const short8v*)&Whl[1][ct * 16 + lm][kb];
            acc[0][ct] = __builtin_amdgcn_mfma_f32_16x16x32_bf16(ah0, bh,
                                                                 acc[0][ct], 0, 0, 0);
            acc[0][ct] = __builtin_amdgcn_mfma_f32_16x16x32_bf16(al0, bh,
                                                                 acc[0][ct], 0, 0, 0);
            acc[0][ct] = __builtin_amdgcn_mfma_f32_16x16x32_bf16(ah0, bl,
                                                                 acc[0][ct], 0, 0, 0);
            acc[1][ct] = __builtin_amdgcn_mfma_f32_16x16x32_bf16(ah1, bh,
                                                                 acc[1][ct], 0, 0, 0);
            acc[1][ct] = __builtin_amdgcn_mfma_f32_16x16x32_bf16(al1, bh,
                                                                 acc[1][ct], 0, 0, 0);
            acc[1][ct] = __builtin_amdgcn_mfma_f32_16x16x32_bf16(ah1, bl,
                                                                 acc[1][ct], 0, 0, 0);
        }
    }

    // Epilogue: scale by invs, store bf16. Per (rt,ct,q) instr: 16 lanes write
    // 32 B contiguous (full 32 B sectors), 4 rows per instr.
    float sc[2][4];
#pragma unroll
    for (int rt = 0; rt < 2; ++rt)
#pragma unroll
        for (int q = 0; q < 4; ++q) {
            int r = rbase + rt * 16 + lk * 4 + q;
            sc[rt][q] = invs[r < N ? r : N - 1];
        }
#pragma unroll
    for (int rt = 0; rt < 2; ++rt)
#pragma unroll
        for (int ct = 0; ct < 8; ++ct)
#pragma unroll
            for (int q = 0; q < 4; ++q) {
                int r = rbase + rt * 16 + lk * 4 + q;
                if (r < N)
                    H[(size_t)r * C + ct * 16 + lm] =
                        f2bf(acc[rt][ct][q] * sc[rt][q]);
            }
}

// ---------------------------------------------------------------------------
// Kernel 2: canonical gather + ELU (UNCHANGED from round 9, 108 us measured).
// ~At the random-gather L3/fabric roofline (~7.5 TB/s effective across very
// different impls in rounds 2 and 9).
// ---------------------------------------------------------------------------
__global__ __launch_bounds__(256) void gather_elu_kernel(
    const unsigned short* __restrict__ H, const int* __restrict__ edge,
    const float* __restrict__ invs, float* __restrict__ out, int N) {
    __shared__ int idx_s[8][K];

    const int t = threadIdx.x;
    const int g = t >> 5;
    const int lane32 = t & 31;
    const int node = blockIdx.x * 8 + g;

    idx_s[g][lane32] = (node < N) ? edge[(size_t)node * K + lane32] : -1;
    __syncthreads();
    if (node >= N) return;

    const unsigned short* hp = H + lane32 * 4;  // this lane's 4 channels
    float a0 = 0.f, a1 = 0.f, a2 = 0.f, a3 = 0.f;

#pragma unroll
    for (int k0 = 0; k0 < K; k0 += 16) {
        ushort4 v[16];
#pragma unroll
        for (int u = 0; u < 16; ++u) {
            int j = idx_s[g][k0 + u];
            j = (j < 0) ? N : j;  // row N is all zeros
            v[u] = *(const ushort4*)(hp + (size_t)j * C);
        }
#pragma unroll
        for (int u = 0; u < 16; ++u) {
            a0 += bf2f(v[u].x);
            a1 += bf2f(v[u].y);
            a2 += bf2f(v[u].z);
            a3 += bf2f(v[u].w);
        }
    }

    ushort4 sv = *(const ushort4*)(hp + (size_t)node * C);
    float s = invs[node];
    float r0 = (a0 + bf2f(sv.x)) * s;
    float r1 = (a1 + bf2f(sv.y)) * s;
    float r2 = (a2 + bf2f(sv.z)) * s;
    float r3 = (a3 + bf2f(sv.w)) * s;
    r0 = r0 > 0.f ? r0 : expm1f(r0);
    r1 = r1 > 0.f ? r1 : expm1f(r1);
    r2 = r2 > 0.f ? r2 : expm1f(r2);
    r3 = r3 > 0.f ? r3 : expm1f(r3);
    float4v rv = {r0, r1, r2, r3};
    *(float4v*)(out + (size_t)node * C + lane32 * 4) = rv;
}

}  // namespace

extern "C" void kernel_launch(void* const* d_in, const int* in_sizes, int n_in,
                              void* d_out, int out_size, void* d_ws, size_t ws_size,
                              hipStream_t stream) {
    const float* x = (const float*)d_in[0];
    const int* edge = (const int*)d_in[1];
    const float* W1 = (const float*)d_in[2];
    const float* W2 = (const float*)d_in[3];
    float* out = (float*)d_out;
    const int N = in_sizes[0] / C;  // 100000

    // Workspace: invs [N floats] | h [(N+1) x 128 bf16, canonical]
    char* ws = (char*)d_ws;
    float* invs = (float*)ws;
    size_t invs_bytes = ((size_t)N * sizeof(float) + 255) & ~(size_t)255;
    unsigned short* h = (unsigned short*)(ws + invs_bytes);

    const int nodeBlocks = (N + 7) / 8;
    const int gemmBlocks = (N + 127) / 128;

    deg_kernel<<<nodeBlocks, 256, 0, stream>>>(edge, invs, (unsigned int*)h, N);
    // Layer 1: x -> h (bf16) -> act (fp32, in d_out)
    gemm_mfma_kernel<<<gemmBlocks, 256, 0, stream>>>(x, W1, invs, h, N);
    gather_elu_kernel<<<nodeBlocks, 256, 0, stream>>>(h, edge, invs, out, N);
    // Layer 2: act (d_out) -> h (bf16) -> out
    gemm_mfma_kernel<<<gemmBlocks, 256, 0, stream>>>(out, W2, invs, h, N);
    gather_elu_kernel<<<nodeBlocks, 256, 0, stream>>>(h, edge, invs, out, N);
}